// Round 1
// 261.289 us; speedup vs baseline: 1.4130x; 1.4130x over previous
//
#include <hip/hip_runtime.h>

typedef unsigned short u16;
typedef unsigned int u32;
typedef __bf16 bf16;
typedef __attribute__((ext_vector_type(8))) __bf16 bf16x8;
typedef __attribute__((ext_vector_type(4))) float f32x4;
typedef __attribute__((ext_vector_type(8))) float f32x8;
typedef __attribute__((ext_vector_type(4))) u16 u16x4;

#define NKPT 80
#define LSPIRAL 41

__device__ __forceinline__ float b2f(u16 v) { return __uint_as_float(((u32)v) << 16); }
__device__ __forceinline__ u16 f2b(float f) {
  u32 u = __float_as_uint(f);
  return (u16)((u + 0x7FFFu + ((u >> 16) & 1u)) >> 16);
}

// One fused conversion pass: x, W1, W2, W3 -> bf16 (segment by flat f32x4 id)
__global__ __launch_bounds__(256)
void cvt_all(const float* __restrict__ x, const float* __restrict__ W1,
             const float* __restrict__ W2, const float* __restrict__ W3,
             u16* __restrict__ xb, u16* __restrict__ W1b,
             u16* __restrict__ W2b, u16* __restrict__ W3b) {
  const int i = blockIdx.x * 256 + threadIdx.x;  // f32x4 index
  const float* src; u16* dst; int off;
  if (i < 32768)        { src = x;  dst = xb;  off = 0; }
  else if (i < 704512)  { src = W1; dst = W1b; off = 32768; }
  else if (i < 1040384) { src = W2; dst = W2b; off = 704512; }
  else if (i < 1124352) { src = W3; dst = W3b; off = 1040384; }
  else return;
  const int j = i - off;
  const f32x4 v = *(const f32x4*)(src + (size_t)j * 4);
  u16x4 o;
#pragma unroll
  for (int t = 0; t < 4; t++) o[t] = f2b(v[t]);
  *(u16x4*)(dst + (size_t)j * 4) = o;
}

// NT GEMM, MFMA 16x16x32 bf16, BK=64, 256 threads (4 waves, 2x2 wave grid).
// Kept verbatim (known-good) for L0 and the small-ws fallback path.
template <int BM, int BN, int GATHER, int LOG2C, int OUTM, int BCVT, int LW>
__global__ __launch_bounds__(256)
void gemm_sp(const u16* __restrict__ A, const void* __restrict__ Wt,
             const int* __restrict__ gidx, float* __restrict__ P,
             u16* __restrict__ Out, const float* __restrict__ bias, int act,
             int N, int K, int itersTotal, int itersPerSplit) {
  constexpr int BK = 64;
  constexpr int WN = BN / 2;
  constexpr int TN = WN / 16;
  constexpr int IA = BM / 32;
  constexpr int IB = BN / 32;
  constexpr int CMASK = (1 << LOG2C) - 1;

  __shared__ u16 As[BM * BK];
  __shared__ u16 Bs[BN * BK];
  __shared__ int idx_s[GATHER ? NKPT * LW : 1];

  const int tid = threadIdx.x;
  const int lane = tid & 63;
  const int wave = tid >> 6;

  const int bm0 = blockIdx.x * BM;
  const int bn0 = blockIdx.y * BN;
  const int split = blockIdx.z;
  const int it0 = split * itersPerSplit;
  const int itEnd = min(itersTotal, it0 + itersPerSplit);
  const int l0 = GATHER ? ((it0 * BK) >> LOG2C) : 0;

  if (GATHER) {
    for (int t = tid; t < NKPT * LW; t += 256) {
      const int n = t / LW;
      const int w = t - n * LW;
      idx_s[t] = gidx[n * LSPIRAL + min(l0 + w, LSPIRAL - 1)];
    }
  }

  const int rIn = lane >> 3;
  const int koff = ((lane & 7) ^ rIn) * 8;

  int aBase[IA];
  const int* aIdxP[IA];
  const u16* aPtr[IA];
  u16* aDst[IA];
#pragma unroll
  for (int i = 0; i < IA; i++) {
    const int q = i * 4 + wave;
    const int r = bm0 + q * 8 + rIn;
    aDst[i] = As + q * 512;
    if (GATHER) {
      const int b = (r * 52429) >> 22;  // r/80 exact for r<10240
      const int n = r - b * 80;
      aBase[i] = (b * NKPT) << LOG2C;
      aIdxP[i] = idx_s + n * LW;
    } else {
      aPtr[i] = A + (size_t)r * K + koff;
    }
  }
  const u16* bPtrH[IB];
  const float* bPtrF[IB];
  u16* bDst[IB];
#pragma unroll
  for (int i = 0; i < IB; i++) {
    const int q = i * 4 + wave;
    const int o = bn0 + q * 8 + rIn;
    bDst[i] = Bs + q * 512;
    if (BCVT) bPtrF[i] = (const float*)Wt + (size_t)o * K + koff;
    else bPtrH[i] = (const u16*)Wt + (size_t)o * K + koff;
  }

  f32x4 acc[4][TN];
#pragma unroll
  for (int i = 0; i < 4; i++)
#pragma unroll
    for (int j = 0; j < TN; j++) acc[i][j] = (f32x4){0.f, 0.f, 0.f, 0.f};

  const int wm = (wave >> 1) * 64;
  const int wn = (wave & 1) * WN;
  const int m15 = lane & 15;
  const int quad = lane >> 4;
  const int fko0 = ((0 + quad) ^ (lane & 7)) * 8;
  const int fko1 = ((4 + quad) ^ (lane & 7)) * 8;

  if (GATHER) __syncthreads();

  bf16x8 curA[IA], nxtA[IA];
  bf16x8 curB[IB], nxtB[IB];
  f32x8 curBF[BCVT ? IB : 1], nxtBF[BCVT ? IB : 1];

  auto loadA = [&](int it, bf16x8* dst) {
    const int k0 = it * BK;
    if (GATHER) {
      const int dl = (k0 >> LOG2C) - l0;
      const int cb = (k0 & CMASK) + koff;
#pragma unroll
      for (int i = 0; i < IA; i++) {
        int J = aIdxP[i][dl];
        J = min(max(J, 0), NKPT - 1);
        dst[i] = *(const bf16x8*)(A + aBase[i] + (J << LOG2C) + cb);
      }
    } else {
#pragma unroll
      for (int i = 0; i < IA; i++) dst[i] = *(const bf16x8*)(aPtr[i] + k0);
    }
  };
  auto loadBH = [&](int it, bf16x8* dst) {
    const int k0 = it * BK;
#pragma unroll
    for (int i = 0; i < IB; i++) dst[i] = *(const bf16x8*)(bPtrH[i] + k0);
  };
  auto loadBF = [&](int it, f32x8* dst) {
    const int k0 = it * BK;
#pragma unroll
    for (int i = 0; i < IB; i++) dst[i] = *(const f32x8*)(bPtrF[i] + k0);
  };

  loadA(it0, curA);
  if (BCVT) loadBF(it0, curBF); else loadBH(it0, curB);

  for (int it = it0; it < itEnd; ++it) {
    __syncthreads();

#pragma unroll
    for (int i = 0; i < IA; i++) *(bf16x8*)(aDst[i] + lane * 8) = curA[i];
    if (BCVT) {
#pragma unroll
      for (int i = 0; i < IB; i++) {
        bf16x8 w;
#pragma unroll
        for (int t = 0; t < 8; t++) w[t] = (bf16)curBF[i][t];
        *(bf16x8*)(bDst[i] + lane * 8) = w;
      }
    } else {
#pragma unroll
      for (int i = 0; i < IB; i++) *(bf16x8*)(bDst[i] + lane * 8) = curB[i];
    }

    __syncthreads();

    const bool more = (it + 1 < itEnd);
    if (more) {
      loadA(it + 1, nxtA);
      if (BCVT) loadBF(it + 1, nxtBF); else loadBH(it + 1, nxtB);
    }

#pragma unroll
    for (int kk = 0; kk < 2; kk++) {
      const int fko = kk ? fko1 : fko0;
      bf16x8 av[4], bv[TN];
#pragma unroll
      for (int i = 0; i < 4; i++)
        av[i] = *(const bf16x8*)(As + (wm + i * 16 + m15) * BK + fko);
#pragma unroll
      for (int j = 0; j < TN; j++)
        bv[j] = *(const bf16x8*)(Bs + (wn + j * 16 + m15) * BK + fko);
#pragma unroll
      for (int i = 0; i < 4; i++)
#pragma unroll
        for (int j = 0; j < TN; j++)
          acc[i][j] = __builtin_amdgcn_mfma_f32_16x16x32_bf16(av[i], bv[j], acc[i][j], 0, 0, 0);
    }

    if (more) {
#pragma unroll
      for (int i = 0; i < IA; i++) curA[i] = nxtA[i];
      if (BCVT) {
#pragma unroll
        for (int i = 0; i < IB; i++) curBF[i] = nxtBF[i];
      } else {
#pragma unroll
        for (int i = 0; i < IB; i++) curB[i] = nxtB[i];
      }
    }
  }

  // C/D layout: col = lane&15, row = quad*4 + reg
#pragma unroll
  for (int i = 0; i < 4; i++) {
    const int r = bm0 + wm + i * 16 + quad * 4;
#pragma unroll
    for (int j = 0; j < TN; j++) {
      const int c = bn0 + wn + j * 16 + m15;
      if (OUTM == 0) {
        const float bv = bias[c];
#pragma unroll
        for (int t = 0; t < 4; t++) {
          float v = acc[i][j][t] + bv;
          if (act) v = v > 0.f ? v : (__expf(v) - 1.f);
          Out[(size_t)(r + t) * N + c] = f2b(v);
        }
      } else {
#pragma unroll
        for (int t = 0; t < 4; t++)
          atomicAdd(P + (size_t)(r + t) * N + c, acc[i][j][t]);
      }
    }
  }
}

// ---------------------------------------------------------------------------
// Spiral decomposition. For node n (frame-local), source j (frame-local):
//   spiral position of j = 0 if j==n, j+1 if j<n, j if j>n; temporal at 40.
// So out[b,n] = S h_n + T h_partner + sum_{j<n} U_j h_j + sum_{j>n} V_j h_j
// with U_j = W[:,(j+1)C], V_j = W[:,jC], S = W[:,0], T = W[:,40C] — all
// column slices of the original weight. Per layer: one grouped GEMM (80
// groups, K=C) producing P2[b*80+j, [U|V|S|T] x Ochunk] in fp32, then a
// prefix/suffix combine pass -> bf16 h_next. FLOPs drop 10.25x vs the
// gather-GEMM (K=41*C -> 4*K=C projections).
// ---------------------------------------------------------------------------

// Grouped GEMM: block = (group j = blockIdx.x in [0,80), N-tile blockIdx.y).
// BM=128 (= batch), BN=128, BK=64, K=C in {128,256}. A row b of group j is
// h[(b*80+j)*C ..]; B row for chunk-col oc: part=oc>>lgOc in {U,V,S,T},
// weight row (o0 + (oc&(Oc-1))), K-offset poff(part,jj). Direct fp32 store
// to P2 (no split-K, no atomics).
__global__ __launch_bounds__(256)
void gemm_grp(const u16* __restrict__ A, const u16* __restrict__ Wb,
              float* __restrict__ P2, const int C, const int ldw,
              const int o0, const int lgOc, const int NC) {
  constexpr int BK = 64;
  __shared__ u16 As[128 * BK];
  __shared__ u16 Bs[128 * BK];

  const int tid = threadIdx.x;
  const int lane = tid & 63;
  const int wave = tid >> 6;
  const int grp = blockIdx.x;               // global node 0..79
  const int jj = grp < 40 ? grp : grp - 40; // frame-local
  const int bn0 = blockIdx.y * 128;
  const int OcM = (1 << lgOc) - 1;

  const int rIn = lane >> 3;
  const int koff = ((lane & 7) ^ rIn) * 8;

  const u16* aPtr[4];
  const u16* bPtr[4];
  u16* aDst[4];
  u16* bDst[4];
#pragma unroll
  for (int i = 0; i < 4; i++) {
    const int q = i * 4 + wave;
    const int rb = q * 8 + rIn;                   // batch index 0..127
    aPtr[i] = A + ((size_t)rb * 80 + grp) * C + koff;
    aDst[i] = As + q * 512;
    const int oc = bn0 + q * 8 + rIn;             // chunk col
    const int part = oc >> lgOc;
    const int orow = o0 + (oc & OcM);
    const int poff = part == 0 ? (jj + 1) * C
                   : part == 1 ? jj * C
                   : part == 2 ? 0
                               : 40 * C;
    bPtr[i] = Wb + (size_t)orow * ldw + poff + koff;
    bDst[i] = Bs + q * 512;
  }

  f32x4 acc[4][4];
#pragma unroll
  for (int i = 0; i < 4; i++)
#pragma unroll
    for (int jn = 0; jn < 4; jn++) acc[i][jn] = (f32x4){0.f, 0.f, 0.f, 0.f};

  const int wm = (wave >> 1) * 64;
  const int wn = (wave & 1) * 64;
  const int m15 = lane & 15;
  const int quad = lane >> 4;
  const int fko0 = ((0 + quad) ^ (lane & 7)) * 8;
  const int fko1 = ((4 + quad) ^ (lane & 7)) * 8;

  const int iters = C >> 6;  // 2 or 4

  bf16x8 curA[4], nxtA[4], curB[4], nxtB[4];
#pragma unroll
  for (int i = 0; i < 4; i++) {
    curA[i] = *(const bf16x8*)(aPtr[i]);
    curB[i] = *(const bf16x8*)(bPtr[i]);
  }

  for (int it = 0; it < iters; ++it) {
    __syncthreads();
#pragma unroll
    for (int i = 0; i < 4; i++) {
      *(bf16x8*)(aDst[i] + lane * 8) = curA[i];
      *(bf16x8*)(bDst[i] + lane * 8) = curB[i];
    }
    __syncthreads();

    const bool more = (it + 1 < iters);
    if (more) {
      const int k0 = (it + 1) * BK;
#pragma unroll
      for (int i = 0; i < 4; i++) {
        nxtA[i] = *(const bf16x8*)(aPtr[i] + k0);
        nxtB[i] = *(const bf16x8*)(bPtr[i] + k0);
      }
    }

#pragma unroll
    for (int kk = 0; kk < 2; kk++) {
      const int fko = kk ? fko1 : fko0;
      bf16x8 av[4], bv[4];
#pragma unroll
      for (int i = 0; i < 4; i++)
        av[i] = *(const bf16x8*)(As + (wm + i * 16 + m15) * BK + fko);
#pragma unroll
      for (int jn = 0; jn < 4; jn++)
        bv[jn] = *(const bf16x8*)(Bs + (wn + jn * 16 + m15) * BK + fko);
#pragma unroll
      for (int i = 0; i < 4; i++)
#pragma unroll
        for (int jn = 0; jn < 4; jn++)
          acc[i][jn] = __builtin_amdgcn_mfma_f32_16x16x32_bf16(av[i], bv[jn], acc[i][jn], 0, 0, 0);
    }

    if (more) {
#pragma unroll
      for (int i = 0; i < 4; i++) { curA[i] = nxtA[i]; curB[i] = nxtB[i]; }
    }
  }

  // C/D layout: col = lane&15, row = quad*4 + reg. Row here = batch b.
#pragma unroll
  for (int i = 0; i < 4; i++) {
    const int rb0 = wm + i * 16 + quad * 4;
#pragma unroll
    for (int jn = 0; jn < 4; jn++) {
      const int c = bn0 + wn + jn * 16 + m15;
#pragma unroll
      for (int t = 0; t < 4; t++)
        P2[((size_t)(rb0 + t) * 80 + grp) * NC + c] = acc[i][jn][t];
    }
  }
}

// Combine: thread = (b, frame f, oc). Reads P2[U|V|S|T], produces all 40
// outputs of (b,f,oc) via prefix-U / suffix-V scan + S(self) + T(partner)
// + bias (+ELU), writes bf16 h_next.
__global__ __launch_bounds__(256)
void combine_k(const float* __restrict__ P2, const float* __restrict__ bias,
               u16* __restrict__ Hout, const int lgOc, const int o0,
               const int Ofull, const int act) {
  const int Oc = 1 << lgOc;
  const int NC = Oc * 4;
  const int t = blockIdx.x * 256 + threadIdx.x;  // total = 128*2*Oc
  const int oc = t & (Oc - 1);
  const int f = (t >> lgOc) & 1;
  const int b = t >> (lgOc + 1);

  const int rowbase = b * 80 + f * 40;
  const float* Pbase = P2 + (size_t)rowbase * NC + oc;   // U at +0
  const float* Vbase = Pbase + Oc;
  const float* Sbase = Pbase + 2 * Oc;
  const float* Tbase = P2 + (size_t)(b * 80 + (1 - f) * 40) * NC + 3 * Oc + oc;
  u16* outp = Hout + (size_t)rowbase * Ofull + o0 + oc;

  float pv[40];
  float totV = 0.f;
#pragma unroll
  for (int j = 0; j < 40; j++) {
    pv[j] = Vbase[j * NC];
    totV += pv[j];
  }
  const float bval = bias[o0 + oc];
  float pre = 0.f, vle = 0.f;
#pragma unroll
  for (int nn = 0; nn < 40; nn++) {
    vle += pv[nn];
    float val = pre + (totV - vle) + Sbase[nn * NC] + Tbase[nn * NC] + bval;
    if (act) val = val > 0.f ? val : (__expf(val) - 1.f);
    outp[nn * Ofull] = f2b(val);
    pre += Pbase[nn * NC];
  }
}

__global__ __launch_bounds__(256)
void final_k(const u16* __restrict__ h3, const float* __restrict__ W4,
             const float* __restrict__ b4, const int* __restrict__ gidx,
             float* __restrict__ out) {
  const int lane = threadIdx.x & 63;
  const int wave = threadIdx.x >> 6;
  const int r = blockIdx.x * 4 + wave;  // < 10240
  const int b = r / 80;
  const int n = r - b * 80;
  const int* ip = gidx + n * LSPIRAL;
  const float* w0 = W4 + lane;
  const float* w1 = W4 + 2624 + lane;
  const u16* hb = h3 + b * (NKPT * 64) + lane;
  float a0 = 0.f, a1 = 0.f;
  for (int l = 0; l < LSPIRAL; l++) {
    int J = ip[l];
    J = min(max(J, 0), NKPT - 1);
    const float hv = b2f(hb[J * 64]);
    a0 += hv * w0[l * 64];
    a1 += hv * w1[l * 64];
  }
#pragma unroll
  for (int off = 32; off > 0; off >>= 1) {
    a0 += __shfl_down(a0, off, 64);
    a1 += __shfl_down(a1, off, 64);
  }
  if (lane == 0) {
    out[r * 2 + 0] = a0 + b4[0];
    out[r * 2 + 1] = a1 + b4[1];
  }
}

extern "C" void kernel_launch(void* const* d_in, const int* in_sizes, int n_in,
                              void* d_out, int out_size, void* d_ws, size_t ws_size,
                              hipStream_t stream) {
  const float* x  = (const float*)d_in[0];
  const float* W0 = (const float*)d_in[1];
  const float* b0 = (const float*)d_in[2];
  const float* W1 = (const float*)d_in[3];
  const float* b1 = (const float*)d_in[4];
  const float* W2 = (const float*)d_in[5];
  const float* b2 = (const float*)d_in[6];
  const float* W3 = (const float*)d_in[7];
  const float* b3 = (const float*)d_in[8];
  const float* W4 = (const float*)d_in[9];
  const float* b4 = (const float*)d_in[10];
  const int* idx = (const int*)d_in[11];
  float* out = (float*)d_out;

  char* ws = (char*)d_ws;
  u16* hA  = (u16*)(ws);                  // 5,242,880 B  (h0, then h2)
  u16* hB  = (u16*)(ws + 5242880);        // 5,242,880 B  (h1, then h3)
  u16* xb  = (u16*)(ws + 10485760);       //   262,144 B
  u16* W1b = (u16*)(ws + 10747904);       // 5,373,952 B
  u16* W2b = (u16*)(ws + 16121856);       // 2,686,976 B
  u16* W3b = (u16*)(ws + 18808832);       //   671,744 B
  float* P = (float*)(ws + 19480576);     // P2 partials: >= 5,242,880 B

  const size_t P2cap = ws_size > (size_t)19480576 ? ws_size - 19480576 : 0;
  const bool full = P2cap >= (size_t)5242880;  // min chunk Oc=32

  if (full) {
    cvt_all<<<4393, 256, 0, stream>>>(x, W1, W2, W3, xb, W1b, W2b, W3b);

    // L0: M=128 N=20480 K=1024, direct bf16 out + bias (no act)
    gemm_sp<128, 64, 0, 0, 0, 1, 1><<<dim3(1, 320, 1), 256, 0, stream>>>(
        xb, W0, idx, nullptr, hA, b0, 0, 20480, 1024, 16, 16);

    // Largest power-of-2 O-chunk whose P2 slab (10240 rows x 4*Oc f32) fits.
    auto pickLg = [&](int O) {
      int lg = 5;  // Oc = 32 -> 5,242,880 B (guaranteed by `full`)
      while ((1 << (lg + 1)) <= O && ((size_t)163840 << (lg + 1)) <= P2cap) lg++;
      return lg;
    };
    auto runLayer = [&](const u16* hin, const u16* wb, const float* bias,
                        u16* hout, int C, int ldw, int O, int act) {
      const int lg = pickLg(O);
      const int Oc = 1 << lg;
      for (int o0 = 0; o0 < O; o0 += Oc) {
        gemm_grp<<<dim3(80, (4 * Oc) / 128), 256, 0, stream>>>(
            hin, wb, P, C, ldw, o0, lg, 4 * Oc);
        combine_k<<<Oc, 256, 0, stream>>>(P, bias, hout, lg, o0, O, act);
      }
    };

    runLayer(hA, W1b, b1, hB, 256, 10496, 256, 1);  // L1: 256 -> 256
    runLayer(hB, W2b, b2, hA, 256, 10496, 128, 1);  // L2: 256 -> 128
    runLayer(hA, W3b, b3, hB, 128, 5248, 64, 1);    // L3: 128 -> 64
  } else {
    // Fallback (<= ~24.7 MB ws): original gather-GEMM path, no split-K.
    cvt_all<<<4393, 256, 0, stream>>>(x, x, x, x, hB, hB, hB, hB);  // only xb part used
    gemm_sp<128, 64, 0, 0, 0, 1, 1><<<dim3(1, 320, 1), 256, 0, stream>>>(
        hB, W0, idx, nullptr, hA, b0, 0, 20480, 1024, 16, 16);
    gemm_sp<128, 128, 1, 8, 0, 1, 44><<<dim3(80, 2, 1), 256, 0, stream>>>(
        hA, W1, idx, nullptr, hB, b1, 1, 256, 10496, 164, 164);
    gemm_sp<128, 128, 1, 8, 0, 1, 44><<<dim3(80, 1, 1), 256, 0, stream>>>(
        hB, W2, idx, nullptr, hA, b2, 1, 128, 10496, 164, 164);
    gemm_sp<128, 64, 1, 7, 0, 1, 44><<<dim3(80, 1, 1), 256, 0, stream>>>(
        hA, W3, idx, nullptr, hB, b3, 1, 64, 5248, 82, 82);
  }

  final_k<<<2560, 256, 0, stream>>>(hB, W4, b4, idx, out);
}